// Round 13
// baseline (77.742 us; speedup 1.0000x reference)
//
#include <hip/hip_runtime.h>
#include <math.h>

// Problem constants
#define B_SZ   16
#define L_SZ   4096
#define NWIN   4092      // (4096-5)/1+1
#define U3     243       // 3^5
#define UPAD   256

// ws layout (float offsets): Apk | M | M partials
#define APK_OFF 0                         // 16384 uint4 (hi 8192, lo 8192)
#define M_OFF   65536
#define EXTRA_OFF (M_OFF + 1048576)       // K-split partial buffers

typedef __attribute__((ext_vector_type(8))) __bf16 bf16x8;
typedef __attribute__((ext_vector_type(4))) float f32x4;

__device__ __forceinline__ float sel3(int t, float c, float s) {
    return t == 0 ? 1.0f : (t == 1 ? c : s);
}

// Apk fragment index for element C[u][v]
__device__ __forceinline__ int apk_idx(int u, int v) {
    return (((u >> 4) * 8 + (v >> 5)) * 64 + ((u & 15) | (((v >> 3) & 3) << 4))) * 8 + (v & 7);
}

// truncation split: x = hi(bf16) + lo(bf16), lo absorbs the error
__device__ __forceinline__ void bfsplit(float x, float& hf, float& lf) {
    hf = __uint_as_float(__float_as_uint(x) & 0xFFFF0000u);
    lf = x - hf;
}

// ---------------- M = E^T (G⊗I) E via MFMA 3-term bf16 split ----------------
// symmetric upper-triangle 64x64 blocks (136), z = K-split S; TILE-32 output layout
__global__ __launch_bounds__(256, 4) void mgemm_ker(const float* __restrict__ E,
                                                    const float* __restrict__ theta,
                                                    float* __restrict__ M,
                                                    float* __restrict__ Mp_extra) {
    __shared__ float SA[32][72];
    __shared__ float SB[32][72];
    __shared__ uint4 AfH[4 * 64], AfL[4 * 64];
    __shared__ uint4 BfH[4 * 64], BfL[4 * 64];

    int t = blockIdx.x;
    int bj = 0;
    while (t >= 16 - bj) { t -= 16 - bj; ++bj; }
    int bk = bj + t;
    int ks = blockIdx.z;
    int tid = threadIdx.x;
    int lane = tid & 63;
    int wave = tid >> 6;

    float th = theta[0];
    float st, ct;
    __sincosf(th, &st, &ct);

    f32x4 acc[4];
    #pragma unroll
    for (int kt = 0; kt < 4; ++kt) acc[kt] = (f32x4){0.f, 0.f, 0.f, 0.f};

    int kchunk = 1024 / gridDim.z;
    int k0 = ks * kchunk;
    int lr = tid >> 3;
    int lcq = (tid & 7) * 8;

    for (int d0 = k0; d0 < k0 + kchunk; d0 += 32) {
        bool hi = d0 >= 512;                         // chunk-uniform for S in {1,2,4}
        int dp = hi ? (d0 - 512) : (d0 + 512);
        float4 a0 = *(const float4*)&E[(d0 + lr) * 1024 + bj * 64 + lcq];
        float4 a1 = *(const float4*)&E[(d0 + lr) * 1024 + bj * 64 + lcq + 4];
        float4 q0 = *(const float4*)&E[(d0 + lr) * 1024 + bk * 64 + lcq];
        float4 q1 = *(const float4*)&E[(d0 + lr) * 1024 + bk * 64 + lcq + 4];
        float4 p0 = *(const float4*)&E[(dp + lr) * 1024 + bk * 64 + lcq];
        float4 p1 = *(const float4*)&E[(dp + lr) * 1024 + bk * 64 + lcq + 4];
        float4 y0, y1;
        if (!hi) {
            y0.x = ct * q0.x - st * p0.x; y0.y = ct * q0.y - st * p0.y;
            y0.z = ct * q0.z - st * p0.z; y0.w = ct * q0.w - st * p0.w;
            y1.x = ct * q1.x - st * p1.x; y1.y = ct * q1.y - st * p1.y;
            y1.z = ct * q1.z - st * p1.z; y1.w = ct * q1.w - st * p1.w;
        } else {
            y0.x = -st * p0.x - ct * q0.x; y0.y = -st * p0.y - ct * q0.y;
            y0.z = -st * p0.z - ct * q0.z; y0.w = -st * p0.w - ct * q0.w;
            y1.x = -st * p1.x - ct * q1.x; y1.y = -st * p1.y - ct * q1.y;
            y1.z = -st * p1.z - ct * q1.z; y1.w = -st * p1.w - ct * q1.w;
        }
        __syncthreads();
        *(float4*)&SA[lr][lcq] = a0;
        *(float4*)&SA[lr][lcq + 4] = a1;
        *(float4*)&SB[lr][lcq] = y0;
        *(float4*)&SB[lr][lcq + 4] = y1;
        __syncthreads();

        {
            unsigned ahw[4], alw[4], bhw[4], blw[4];
            float pah, pal, pbh, pbl;
            #pragma unroll
            for (int i = 0; i < 8; ++i) {
                float av = SA[wave * 8 + i][lane];
                float bv = SB[wave * 8 + i][lane];
                float ah, al, bh, bl;
                bfsplit(av, ah, al);
                bfsplit(bv, bh, bl);
                if (i & 1) {
                    ahw[i >> 1] = __byte_perm(__float_as_uint(pah), __float_as_uint(ah), 0x7632);
                    alw[i >> 1] = __byte_perm(__float_as_uint(pal), __float_as_uint(al), 0x7632);
                    bhw[i >> 1] = __byte_perm(__float_as_uint(pbh), __float_as_uint(bh), 0x7632);
                    blw[i >> 1] = __byte_perm(__float_as_uint(pbl), __float_as_uint(bl), 0x7632);
                } else { pah = ah; pal = al; pbh = bh; pbl = bl; }
            }
            int slot = ((lane >> 4) << 6) + (lane & 15) + (wave << 4);
            AfH[slot] = make_uint4(ahw[0], ahw[1], ahw[2], ahw[3]);
            AfL[slot] = make_uint4(alw[0], alw[1], alw[2], alw[3]);
            BfH[slot] = make_uint4(bhw[0], bhw[1], bhw[2], bhw[3]);
            BfL[slot] = make_uint4(blw[0], blw[1], blw[2], blw[3]);
        }
        __syncthreads();

        uint4 ahu = AfH[wave * 64 + lane];
        uint4 alu = AfL[wave * 64 + lane];
        bf16x8 ah = __builtin_bit_cast(bf16x8, ahu);
        bf16x8 al = __builtin_bit_cast(bf16x8, alu);
        #pragma unroll
        for (int kt = 0; kt < 4; ++kt) {
            uint4 bhu = BfH[kt * 64 + lane];
            uint4 blu = BfL[kt * 64 + lane];
            bf16x8 bh = __builtin_bit_cast(bf16x8, bhu);
            bf16x8 bl = __builtin_bit_cast(bf16x8, blu);
            acc[kt] = __builtin_amdgcn_mfma_f32_16x16x32_bf16(ah, bh, acc[kt], 0, 0, 0);
            acc[kt] = __builtin_amdgcn_mfma_f32_16x16x32_bf16(ah, bl, acc[kt], 0, 0, 0);
            acc[kt] = __builtin_amdgcn_mfma_f32_16x16x32_bf16(al, bh, acc[kt], 0, 0, 0);
        }
    }

    float* dst = (ks == 0) ? M : (Mp_extra + (ks - 1) * 1048576);
    #pragma unroll
    for (int kt = 0; kt < 4; ++kt) {
        #pragma unroll
        for (int i = 0; i < 4; ++i) {
            int r = bj * 64 + wave * 16 + ((lane >> 4) << 2) + i;
            int c = bk * 64 + kt * 16 + (lane & 15);
            dst[((r >> 5) * 32 + (c >> 5)) * 1024 + (r & 31) * 32 + (c & 31)] = acc[kt][i];
        }
    }
}

// ---------------- C via WHT, scattering bf16 hi/lo into Apk; mx==0 also zeroes pads ----------------
__global__ __launch_bounds__(256) void cwht_ker(const float* __restrict__ M,
                                                const float* __restrict__ Mp_extra,
                                                int S,
                                                unsigned short* __restrict__ ApkH) {
    __shared__ float D[1024];
    int mx = blockIdx.x;
    int mxh = mx >> 5, mxl = mx & 31;
    int tid = threadIdx.x;
    float v[4];
    #pragma unroll
    for (int k = 0; k < 4; ++k) {
        int j = tid + k * 256;
        int jh = j >> 5, jl = j & 31;
        int kh = jh ^ mxh, kl = jl ^ mxl;
        int off;
        if ((jh >> 1) <= (kh >> 1)) off = ((jh * 32 + kh) * 32 + jl) * 32 + kl;
        else                        off = ((kh * 32 + jh) * 32 + kl) * 32 + jl;
        float t = M[off];
        for (int s = 1; s < S; ++s) t += Mp_extra[(s - 1) * 1048576 + off];
        v[k] = t;
    }
    #pragma unroll
    for (int s = 0; s < 6; ++s) {
        int bit = (tid >> s) & 1;
        #pragma unroll
        for (int k = 0; k < 4; ++k) {
            float p = __shfl_xor(v[k], 1 << s, 64);
            v[k] = bit ? (p - v[k]) : (v[k] + p);
        }
    }
    #pragma unroll
    for (int k = 0; k < 4; ++k) D[tid + k * 256] = v[k];
    __syncthreads();
    {
        int b6 = (tid >> 6) & 1, b7 = (tid >> 7) & 1;
        #pragma unroll
        for (int k = 0; k < 4; ++k) {
            float p64  = D[(tid ^ 64)  + k * 256];
            float p128 = D[(tid ^ 128) + k * 256];
            float p192 = D[(tid ^ 192) + k * 256];
            float ta = b6 ? (p64 - v[k])   : (v[k] + p64);
            float tb = b6 ? (p192 - p128)  : (p128 + p192);
            v[k] = b7 ? (tb - ta) : (ta + tb);
        }
    }
    {
        float a0 = v[0] + v[1], a1 = v[0] - v[1], a2 = v[2] + v[3], a3 = v[2] - v[3];
        v[0] = a0 + a2; v[1] = a1 + a3; v[2] = a0 - a2; v[3] = a1 - a3;
    }
    #pragma unroll
    for (int k = 0; k < 4; ++k) {
        int mz = tid + k * 256;
        if (mz & mx) continue;
        int u = 0, vv = 0;
        #pragma unroll
        for (int i = 0; i < 5; ++i) {
            int bit = 9 - i;
            int tt = ((mx >> bit) & 1) ? 2 : (((mz >> bit) & 1) ? 1 : 0);
            u = u * 3 + tt;
        }
        #pragma unroll
        for (int i = 5; i < 10; ++i) {
            int bit = 9 - i;
            int tt = ((mx >> bit) & 1) ? 2 : (((mz >> bit) & 1) ? 1 : 0);
            vv = vv * 3 + tt;
        }
        float val = v[k] * (1.0f / 1024.0f);
        unsigned hh = __float_as_uint(val) & 0xFFFF0000u;
        float lf = val - __uint_as_float(hh);
        unsigned ll = __float_as_uint(lf) >> 16;
        int idx = apk_idx(u, vv);
        ApkH[idx] = (unsigned short)(hh >> 16);
        ApkH[idx + 65536] = (unsigned short)ll;
    }
    if (mx == 0) {
        for (int e = tid; e < 13 * 256; e += 256) {
            int u = 243 + (e >> 8), vv = e & 255;
            int idx = apk_idx(u, vv);
            ApkH[idx] = 0; ApkH[idx + 65536] = 0;
        }
        for (int e = tid; e < 243 * 13; e += 256) {
            int u = e / 13, vv = 243 + (e - (e / 13) * 13);
            int idx = apk_idx(u, vv);
            ApkH[idx] = 0; ApkH[idx + 65536] = 0;
        }
    }
}

// ---------------- main: 64 windows/block, MFMA 16x16x32 bf16 3-term split ----------------
// PHASE-STAGGERED by block parity: odd blocks run half h=1 first and epilogue hp=1 first
// (accumulation order-independent) so co-resident blocks' VALU/LDS/MFMA phases overlap
// instead of convoying. F1 scalar-walk build; F0 via LDS table; lb(256,3) keeps acc resident.
__global__ __launch_bounds__(256, 3) void main_ker(const float* __restrict__ x,
                                                   const uint4* __restrict__ Apk,
                                                   float* __restrict__ out) {
    __shared__ float trg[4][68];
    __shared__ __align__(16) unsigned char arena[33280];
    unsigned short* F1h = (unsigned short*)arena;
    unsigned short* F1l = (unsigned short*)(arena + 16640);
    float* F0 = (float*)arena;
    __shared__ float red[16][16];

    int tid = threadIdx.x;
    int w0 = blockIdx.x * 64;
    int b  = blockIdx.y;
    int lane = tid & 63;
    int wave = tid >> 6;
    int wb = tid & 63;
    int wu = __builtin_amdgcn_readfirstlane(wave);
    int ph = (blockIdx.x ^ (blockIdx.y >> 2)) & 1;   // stagger parity (flips within a CU's co-resident set)

    for (int p = tid; p < 68; p += 256) {
        int pos = w0 + p;
        bool ok = pos < L_SZ;
        float x1 = ok ? x[b * 8192 + 4096 + pos] : 0.f;
        float x0 = ok ? x[b * 8192 + pos] : 0.f;
        float c1v, s1v, c0v, s0v;
        __sincosf(x1, &s1v, &c1v);
        __sincosf(x0, &s0v, &c0v);
        if (!ok) { c1v = 0.f; s1v = 0.f; c0v = 0.f; s0v = 0.f; }
        trg[0][p] = c1v; trg[1][p] = s1v; trg[2][p] = c0v; trg[3][p] = s0v;
    }

    f32x4 acc[4][4];
    #pragma unroll
    for (int ut = 0; ut < 4; ++ut)
        #pragma unroll
        for (int wt = 0; wt < 4; ++wt)
            acc[ut][wt] = (f32x4){0.f, 0.f, 0.f, 0.f};

    __syncthreads();

    float c1r[5], s1r[5];
    #pragma unroll
    for (int k = 0; k < 5; ++k) { c1r[k] = trg[0][wb + k]; s1r[k] = trg[1][wb + k]; }

    const uint4* Ahi = Apk;
    const uint4* Alo = Apk + 8192;

    #pragma unroll 1
    for (int hh = 0; hh < 2; ++hh) {
        int h = hh ^ ph;                             // staggered half order
        if (hh) __syncthreads();
        // ---- build F1 half h: 32 v per thread, scalar digit walk ----
        {
            int gv = h * 128 + wu * 32;
            int t0 = gv / 81; int rr = gv - t0 * 81;
            int t1 = rr / 27; rr -= t1 * 27;
            int t2 = rr / 9;  rr -= t2 * 9;
            int t3 = rr / 3;  int t4 = rr - t3 * 3;
            float g0 = sel3(t0, c1r[0], s1r[0]);
            float g1 = sel3(t1, c1r[1], s1r[1]);
            float g2 = sel3(t2, c1r[2], s1r[2]);
            float g3 = sel3(t3, c1r[3], s1r[3]);
            float p0123 = g0 * g1 * g2 * g3;
            #pragma unroll
            for (int p8 = 0; p8 < 4; ++p8) {
                unsigned hw[4], lw[4];
                float prevh, prevl;
                #pragma unroll
                for (int i = 0; i < 8; ++i) {
                    float val = p0123 * sel3(t4, c1r[4], s1r[4]);
                    float hf, lf;
                    bfsplit(val, hf, lf);
                    if (i & 1) {
                        hw[i >> 1] = __byte_perm(__float_as_uint(prevh), __float_as_uint(hf), 0x7632);
                        lw[i >> 1] = __byte_perm(__float_as_uint(prevl), __float_as_uint(lf), 0x7632);
                    } else { prevh = hf; prevl = lf; }
                    if (++t4 == 3) { t4 = 0;
                        if (++t3 == 3) { t3 = 0;
                            if (++t2 == 3) { t2 = 0;
                                if (++t1 == 3) { t1 = 0; ++t0; g0 = sel3(t0, c1r[0], s1r[0]); }
                                g1 = sel3(t1, c1r[1], s1r[1]);
                            }
                            g2 = sel3(t2, c1r[2], s1r[2]);
                        }
                        g3 = sel3(t3, c1r[3], s1r[3]);
                        p0123 = g0 * g1 * g2 * g3;
                    }
                }
                int vp = wu * 4 + p8;
                *(uint4*)&F1h[(vp * 65 + wb) * 8] = make_uint4(hw[0], hw[1], hw[2], hw[3]);
                *(uint4*)&F1l[(vp * 65 + wb) * 8] = make_uint4(lw[0], lw[1], lw[2], lw[3]);
            }
        }
        __syncthreads();

        // ---- MFMA over this half's 4 K-steps ----
        #pragma unroll
        for (int kl = 0; kl < 4; ++kl) {
            int ks = h * 4 + kl;
            uint4 a_h[4], a_l[4];
            #pragma unroll
            for (int ut = 0; ut < 4; ++ut) {
                int idx = ((wave * 4 + ut) * 8 + ks) * 64 + lane;
                a_h[ut] = Ahi[idx];
                a_l[ut] = Alo[idx];
            }
            int vp = kl * 4 + (lane >> 4);
            #pragma unroll
            for (int wt = 0; wt < 4; ++wt) {
                int off = (vp * 65 + wt * 16 + (lane & 15)) * 8;
                uint4 b_h = *(const uint4*)&F1h[off];
                uint4 b_l = *(const uint4*)&F1l[off];
                bf16x8 bh = __builtin_bit_cast(bf16x8, b_h);
                bf16x8 bl = __builtin_bit_cast(bf16x8, b_l);
                #pragma unroll
                for (int ut = 0; ut < 4; ++ut) {
                    bf16x8 ah = __builtin_bit_cast(bf16x8, a_h[ut]);
                    bf16x8 al = __builtin_bit_cast(bf16x8, a_l[ut]);
                    acc[ut][wt] = __builtin_amdgcn_mfma_f32_16x16x32_bf16(ah, bh, acc[ut][wt], 0, 0, 0);
                    acc[ut][wt] = __builtin_amdgcn_mfma_f32_16x16x32_bf16(ah, bl, acc[ut][wt], 0, 0, 0);
                    acc[ut][wt] = __builtin_amdgcn_mfma_f32_16x16x32_bf16(al, bh, acc[ut][wt], 0, 0, 0);
                }
            }
        }
    }

    // ---- epilogue: z[w] = sum_u F0[u,w]*G[u,w] via LDS F0 table, staggered hp order ----
    int c = lane & 15;
    float c0b[5], s0b[5];
    #pragma unroll
    for (int k = 0; k < 5; ++k) { c0b[k] = trg[2][wb + k]; s0b[k] = trg[3][wb + k]; }
    float zcol[4] = {0.f, 0.f, 0.f, 0.f};

    __syncthreads();
    #pragma unroll 1
    for (int hh = 0; hh < 2; ++hh) {
        int hp = hh ^ ph;                            // staggered epilogue order
        if (hh) __syncthreads();
        {
            int gu = hp * 128 + wu * 32;
            int t0 = gu / 81; int rr = gu - t0 * 81;
            int t1 = rr / 27; rr -= t1 * 27;
            int t2 = rr / 9;  rr -= t2 * 9;
            int t3 = rr / 3;  int t4 = rr - t3 * 3;
            float g0 = sel3(t0, c0b[0], s0b[0]);
            float g1 = sel3(t1, c0b[1], s0b[1]);
            float g2 = sel3(t2, c0b[2], s0b[2]);
            float g3 = sel3(t3, c0b[3], s0b[3]);
            float p0123 = g0 * g1 * g2 * g3;
            #pragma unroll
            for (int s = 0; s < 32; ++s) {
                float val = p0123 * sel3(t4, c0b[4], s0b[4]);
                F0[(wu * 32 + s) * 65 + wb] = val;
                if (++t4 == 3) { t4 = 0;
                    if (++t3 == 3) { t3 = 0;
                        if (++t2 == 3) { t2 = 0;
                            if (++t1 == 3) { t1 = 0; ++t0; g0 = sel3(t0, c0b[0], s0b[0]); }
                            g1 = sel3(t1, c0b[1], s0b[1]);
                        }
                        g2 = sel3(t2, c0b[2], s0b[2]);
                    }
                    g3 = sel3(t3, c0b[3], s0b[3]);
                    p0123 = g0 * g1 * g2 * g3;
                }
            }
        }
        __syncthreads();
        if ((wave >> 1) == hp) {
            int wloc = wave & 1;
            int qb = (lane >> 4) << 2;
            #pragma unroll
            for (int ut = 0; ut < 4; ++ut) {
                #pragma unroll
                for (int r = 0; r < 4; ++r) {
                    int uloc = wloc * 64 + ut * 16 + qb + r;
                    #pragma unroll
                    for (int wt = 0; wt < 4; ++wt)
                        zcol[wt] += F0[uloc * 65 + wt * 16 + c] * acc[ut][wt][r];
                }
            }
        }
    }

    // ---- reduce over u-groups ----
    #pragma unroll
    for (int wt = 0; wt < 4; ++wt) {
        float v = zcol[wt];
        v += __shfl_xor(v, 16, 64);
        v += __shfl_xor(v, 32, 64);
        if ((lane >> 4) == 0) red[wave * 4 + wt][lane] = v;
    }
    __syncthreads();
    if (tid < 64) {
        int wt = tid >> 4, cc = tid & 15;
        float z = red[0 * 4 + wt][cc] + red[1 * 4 + wt][cc]
                + red[2 * 4 + wt][cc] + red[3 * 4 + wt][cc];
        int w = wt * 16 + cc;
        if (w0 + w < NWIN) out[b * NWIN + w0 + w] = z;
    }
}

extern "C" void kernel_launch(void* const* d_in, const int* in_sizes, int n_in,
                              void* d_out, int out_size, void* d_ws, size_t ws_size,
                              hipStream_t stream) {
    const float* x     = (const float*)d_in[0];
    const float* E     = (const float*)d_in[1];
    const float* theta = (const float*)d_in[2];
    float* out = (float*)d_out;
    float* ws = (float*)d_ws;

    uint4* Apk = (uint4*)(ws + APK_OFF);
    float* M   = ws + M_OFF;
    float* Mx  = ws + EXTRA_OFF;

    size_t need4 = (size_t)(EXTRA_OFF + 3 * 1048576) * 4;
    size_t need2 = (size_t)(EXTRA_OFF + 1 * 1048576) * 4;
    int S = (ws_size >= need4) ? 4 : ((ws_size >= need2) ? 2 : 1);

    mgemm_ker<<<dim3(136, 1, S), 256, 0, stream>>>(E, theta, M, Mx);
    cwht_ker<<<1024, 256, 0, stream>>>(M, Mx, S, (unsigned short*)Apk);
    main_ker<<<dim3(64, 16), 256, 0, stream>>>(x, Apk, out);
}

// Round 14
// 70.619 us; speedup vs baseline: 1.1009x; 1.1009x over previous
//
#include <hip/hip_runtime.h>
#include <math.h>

// Problem constants
#define B_SZ   16
#define L_SZ   4096
#define NWIN   4092      // (4096-5)/1+1
#define U3     243       // 3^5
#define UPAD   256

// ws layout (float offsets): Apk | M | M partials
#define APK_OFF 0                         // 16384 uint4 (hi 8192, lo 8192)
#define M_OFF   65536
#define EXTRA_OFF (M_OFF + 1048576)       // K-split partial buffers

typedef __attribute__((ext_vector_type(8))) __bf16 bf16x8;
typedef __attribute__((ext_vector_type(4))) float f32x4;

__device__ __forceinline__ float sel3(int t, float c, float s) {
    return t == 0 ? 1.0f : (t == 1 ? c : s);
}

// Apk fragment index for element C[u][v]
__device__ __forceinline__ int apk_idx(int u, int v) {
    return (((u >> 4) * 8 + (v >> 5)) * 64 + ((u & 15) | (((v >> 3) & 3) << 4))) * 8 + (v & 7);
}

// truncation split: x = hi(bf16) + lo(bf16), lo absorbs the error
__device__ __forceinline__ void bfsplit(float x, float& hf, float& lf) {
    hf = __uint_as_float(__float_as_uint(x) & 0xFFFF0000u);
    lf = x - hf;
}

// ---------------- M = E^T (G⊗I) E via MFMA 3-term bf16 split ----------------
// symmetric upper-triangle 64x64 blocks (136), z = K-split S; TILE-32 output layout
__global__ __launch_bounds__(256, 4) void mgemm_ker(const float* __restrict__ E,
                                                    const float* __restrict__ theta,
                                                    float* __restrict__ M,
                                                    float* __restrict__ Mp_extra) {
    __shared__ float SA[32][72];
    __shared__ float SB[32][72];
    __shared__ uint4 AfH[4 * 64], AfL[4 * 64];
    __shared__ uint4 BfH[4 * 64], BfL[4 * 64];

    int t = blockIdx.x;
    int bj = 0;
    while (t >= 16 - bj) { t -= 16 - bj; ++bj; }
    int bk = bj + t;
    int ks = blockIdx.z;
    int tid = threadIdx.x;
    int lane = tid & 63;
    int wave = tid >> 6;

    float th = theta[0];
    float st, ct;
    __sincosf(th, &st, &ct);

    f32x4 acc[4];
    #pragma unroll
    for (int kt = 0; kt < 4; ++kt) acc[kt] = (f32x4){0.f, 0.f, 0.f, 0.f};

    int kchunk = 1024 / gridDim.z;
    int k0 = ks * kchunk;
    int lr = tid >> 3;
    int lcq = (tid & 7) * 8;

    for (int d0 = k0; d0 < k0 + kchunk; d0 += 32) {
        bool hi = d0 >= 512;
        int dp = hi ? (d0 - 512) : (d0 + 512);
        float4 a0 = *(const float4*)&E[(d0 + lr) * 1024 + bj * 64 + lcq];
        float4 a1 = *(const float4*)&E[(d0 + lr) * 1024 + bj * 64 + lcq + 4];
        float4 q0 = *(const float4*)&E[(d0 + lr) * 1024 + bk * 64 + lcq];
        float4 q1 = *(const float4*)&E[(d0 + lr) * 1024 + bk * 64 + lcq + 4];
        float4 p0 = *(const float4*)&E[(dp + lr) * 1024 + bk * 64 + lcq];
        float4 p1 = *(const float4*)&E[(dp + lr) * 1024 + bk * 64 + lcq + 4];
        float4 y0, y1;
        if (!hi) {
            y0.x = ct * q0.x - st * p0.x; y0.y = ct * q0.y - st * p0.y;
            y0.z = ct * q0.z - st * p0.z; y0.w = ct * q0.w - st * p0.w;
            y1.x = ct * q1.x - st * p1.x; y1.y = ct * q1.y - st * p1.y;
            y1.z = ct * q1.z - st * p1.z; y1.w = ct * q1.w - st * p1.w;
        } else {
            y0.x = -st * p0.x - ct * q0.x; y0.y = -st * p0.y - ct * q0.y;
            y0.z = -st * p0.z - ct * q0.z; y0.w = -st * p0.w - ct * q0.w;
            y1.x = -st * p1.x - ct * q1.x; y1.y = -st * p1.y - ct * q1.y;
            y1.z = -st * p1.z - ct * q1.z; y1.w = -st * p1.w - ct * q1.w;
        }
        __syncthreads();
        *(float4*)&SA[lr][lcq] = a0;
        *(float4*)&SA[lr][lcq + 4] = a1;
        *(float4*)&SB[lr][lcq] = y0;
        *(float4*)&SB[lr][lcq + 4] = y1;
        __syncthreads();

        {
            unsigned ahw[4], alw[4], bhw[4], blw[4];
            float pah, pal, pbh, pbl;
            #pragma unroll
            for (int i = 0; i < 8; ++i) {
                float av = SA[wave * 8 + i][lane];
                float bv = SB[wave * 8 + i][lane];
                float ah, al, bh, bl;
                bfsplit(av, ah, al);
                bfsplit(bv, bh, bl);
                if (i & 1) {
                    ahw[i >> 1] = __byte_perm(__float_as_uint(pah), __float_as_uint(ah), 0x7632);
                    alw[i >> 1] = __byte_perm(__float_as_uint(pal), __float_as_uint(al), 0x7632);
                    bhw[i >> 1] = __byte_perm(__float_as_uint(pbh), __float_as_uint(bh), 0x7632);
                    blw[i >> 1] = __byte_perm(__float_as_uint(pbl), __float_as_uint(bl), 0x7632);
                } else { pah = ah; pal = al; pbh = bh; pbl = bl; }
            }
            int slot = ((lane >> 4) << 6) + (lane & 15) + (wave << 4);
            AfH[slot] = make_uint4(ahw[0], ahw[1], ahw[2], ahw[3]);
            AfL[slot] = make_uint4(alw[0], alw[1], alw[2], alw[3]);
            BfH[slot] = make_uint4(bhw[0], bhw[1], bhw[2], bhw[3]);
            BfL[slot] = make_uint4(blw[0], blw[1], blw[2], blw[3]);
        }
        __syncthreads();

        uint4 ahu = AfH[wave * 64 + lane];
        uint4 alu = AfL[wave * 64 + lane];
        bf16x8 ah = __builtin_bit_cast(bf16x8, ahu);
        bf16x8 al = __builtin_bit_cast(bf16x8, alu);
        #pragma unroll
        for (int kt = 0; kt < 4; ++kt) {
            uint4 bhu = BfH[kt * 64 + lane];
            uint4 blu = BfL[kt * 64 + lane];
            bf16x8 bh = __builtin_bit_cast(bf16x8, bhu);
            bf16x8 bl = __builtin_bit_cast(bf16x8, blu);
            acc[kt] = __builtin_amdgcn_mfma_f32_16x16x32_bf16(ah, bh, acc[kt], 0, 0, 0);
            acc[kt] = __builtin_amdgcn_mfma_f32_16x16x32_bf16(ah, bl, acc[kt], 0, 0, 0);
            acc[kt] = __builtin_amdgcn_mfma_f32_16x16x32_bf16(al, bh, acc[kt], 0, 0, 0);
        }
    }

    float* dst = (ks == 0) ? M : (Mp_extra + (ks - 1) * 1048576);
    #pragma unroll
    for (int kt = 0; kt < 4; ++kt) {
        #pragma unroll
        for (int i = 0; i < 4; ++i) {
            int r = bj * 64 + wave * 16 + ((lane >> 4) << 2) + i;
            int c = bk * 64 + kt * 16 + (lane & 15);
            dst[((r >> 5) * 32 + (c >> 5)) * 1024 + (r & 31) * 32 + (c & 31)] = acc[kt][i];
        }
    }
}

// ---------------- sum K-split partials into M (coalesced) ----------------
__global__ __launch_bounds__(256) void sum_ker(float* __restrict__ M,
                                               const float* __restrict__ Mp_extra,
                                               int S) {
    int i = blockIdx.x * 256 + threadIdx.x;   // < 262144 float4
    float4 v = ((const float4*)M)[i];
    for (int s = 1; s < S; ++s) {
        float4 p = ((const float4*)(Mp_extra + (s - 1) * 1048576))[i];
        v.x += p.x; v.y += p.y; v.z += p.z; v.w += p.w;
    }
    ((float4*)M)[i] = v;
}

// ---------------- C via WHT (single summed M), scattering bf16 hi/lo into Apk ----------------
__global__ __launch_bounds__(256) void cwht_ker(const float* __restrict__ M,
                                                unsigned short* __restrict__ ApkH) {
    __shared__ float D[1024];
    int mx = blockIdx.x;
    int mxh = mx >> 5, mxl = mx & 31;
    int tid = threadIdx.x;
    float v[4];
    #pragma unroll
    for (int k = 0; k < 4; ++k) {
        int j = tid + k * 256;
        int jh = j >> 5, jl = j & 31;
        int kh = jh ^ mxh, kl = jl ^ mxl;
        int off;
        if ((jh >> 1) <= (kh >> 1)) off = ((jh * 32 + kh) * 32 + jl) * 32 + kl;
        else                        off = ((kh * 32 + jh) * 32 + kl) * 32 + jl;  // symmetric image
        v[k] = M[off];
    }
    #pragma unroll
    for (int s = 0; s < 6; ++s) {
        int bit = (tid >> s) & 1;
        #pragma unroll
        for (int k = 0; k < 4; ++k) {
            float p = __shfl_xor(v[k], 1 << s, 64);
            v[k] = bit ? (p - v[k]) : (v[k] + p);
        }
    }
    #pragma unroll
    for (int k = 0; k < 4; ++k) D[tid + k * 256] = v[k];
    __syncthreads();
    {
        int b6 = (tid >> 6) & 1, b7 = (tid >> 7) & 1;
        #pragma unroll
        for (int k = 0; k < 4; ++k) {
            float p64  = D[(tid ^ 64)  + k * 256];
            float p128 = D[(tid ^ 128) + k * 256];
            float p192 = D[(tid ^ 192) + k * 256];
            float ta = b6 ? (p64 - v[k])   : (v[k] + p64);
            float tb = b6 ? (p192 - p128)  : (p128 + p192);
            v[k] = b7 ? (tb - ta) : (ta + tb);
        }
    }
    {
        float a0 = v[0] + v[1], a1 = v[0] - v[1], a2 = v[2] + v[3], a3 = v[2] - v[3];
        v[0] = a0 + a2; v[1] = a1 + a3; v[2] = a0 - a2; v[3] = a1 - a3;
    }
    #pragma unroll
    for (int k = 0; k < 4; ++k) {
        int mz = tid + k * 256;
        if (mz & mx) continue;
        int u = 0, vv = 0;
        #pragma unroll
        for (int i = 0; i < 5; ++i) {
            int bit = 9 - i;
            int tt = ((mx >> bit) & 1) ? 2 : (((mz >> bit) & 1) ? 1 : 0);
            u = u * 3 + tt;
        }
        #pragma unroll
        for (int i = 5; i < 10; ++i) {
            int bit = 9 - i;
            int tt = ((mx >> bit) & 1) ? 2 : (((mz >> bit) & 1) ? 1 : 0);
            vv = vv * 3 + tt;
        }
        float val = v[k] * (1.0f / 1024.0f);
        unsigned hh = __float_as_uint(val) & 0xFFFF0000u;
        float lf = val - __uint_as_float(hh);
        unsigned ll = __float_as_uint(lf) >> 16;
        int idx = apk_idx(u, vv);
        ApkH[idx] = (unsigned short)(hh >> 16);
        ApkH[idx + 65536] = (unsigned short)ll;
    }
    if (mx == 0) {
        for (int e = tid; e < 13 * 256; e += 256) {
            int u = 243 + (e >> 8), vv = e & 255;
            int idx = apk_idx(u, vv);
            ApkH[idx] = 0; ApkH[idx + 65536] = 0;
        }
        for (int e = tid; e < 243 * 13; e += 256) {
            int u = e / 13, vv = 243 + (e - (e / 13) * 13);
            int idx = apk_idx(u, vv);
            ApkH[idx] = 0; ApkH[idx + 65536] = 0;
        }
    }
}

// ---------------- main: 64 windows/block, MFMA 16x16x32 bf16 3-term split ----------------
// EXPLICIT 1-DEEP A-FRAG PREFETCH: next-ks A loads issued before current-ks MFMAs
// (cross-h prefetch hidden under F1 build). lb(256,2): 256-VGPR budget, no spill.
__global__ __launch_bounds__(256, 2) void main_ker(const float* __restrict__ x,
                                                   const uint4* __restrict__ Apk,
                                                   float* __restrict__ out) {
    __shared__ float trg[4][68];
    __shared__ __align__(16) unsigned char arena[33280];
    unsigned short* F1h = (unsigned short*)arena;
    unsigned short* F1l = (unsigned short*)(arena + 16640);
    float* F0 = (float*)arena;
    __shared__ float red[16][16];

    int tid = threadIdx.x;
    int w0 = blockIdx.x * 64;
    int b  = blockIdx.y;
    int lane = tid & 63;
    int wave = tid >> 6;
    int wb = tid & 63;
    int wu = __builtin_amdgcn_readfirstlane(wave);

    for (int p = tid; p < 68; p += 256) {
        int pos = w0 + p;
        bool ok = pos < L_SZ;
        float x1 = ok ? x[b * 8192 + 4096 + pos] : 0.f;
        float x0 = ok ? x[b * 8192 + pos] : 0.f;
        float c1v, s1v, c0v, s0v;
        __sincosf(x1, &s1v, &c1v);
        __sincosf(x0, &s0v, &c0v);
        if (!ok) { c1v = 0.f; s1v = 0.f; c0v = 0.f; s0v = 0.f; }
        trg[0][p] = c1v; trg[1][p] = s1v; trg[2][p] = c0v; trg[3][p] = s0v;
    }

    f32x4 acc[4][4];
    #pragma unroll
    for (int ut = 0; ut < 4; ++ut)
        #pragma unroll
        for (int wt = 0; wt < 4; ++wt)
            acc[ut][wt] = (f32x4){0.f, 0.f, 0.f, 0.f};

    __syncthreads();

    float c1r[5], s1r[5];
    #pragma unroll
    for (int k = 0; k < 5; ++k) { c1r[k] = trg[0][wb + k]; s1r[k] = trg[1][wb + k]; }

    const uint4* Ahi = Apk;
    const uint4* Alo = Apk + 8192;

    // prefetch A-frags for ks=0 (in flight during the h=0 F1 build)
    uint4 a_h[4], a_l[4];
    #pragma unroll
    for (int ut = 0; ut < 4; ++ut) {
        int idx = ((wave * 4 + ut) * 8 + 0) * 64 + lane;
        a_h[ut] = Ahi[idx];
        a_l[ut] = Alo[idx];
    }

    #pragma unroll 1
    for (int h = 0; h < 2; ++h) {
        if (h) __syncthreads();
        // ---- build F1 half h: 32 v per thread, scalar digit walk ----
        {
            int gv = h * 128 + wu * 32;
            int t0 = gv / 81; int rr = gv - t0 * 81;
            int t1 = rr / 27; rr -= t1 * 27;
            int t2 = rr / 9;  rr -= t2 * 9;
            int t3 = rr / 3;  int t4 = rr - t3 * 3;
            float g0 = sel3(t0, c1r[0], s1r[0]);
            float g1 = sel3(t1, c1r[1], s1r[1]);
            float g2 = sel3(t2, c1r[2], s1r[2]);
            float g3 = sel3(t3, c1r[3], s1r[3]);
            float p0123 = g0 * g1 * g2 * g3;
            #pragma unroll
            for (int p8 = 0; p8 < 4; ++p8) {
                unsigned hw[4], lw[4];
                float prevh, prevl;
                #pragma unroll
                for (int i = 0; i < 8; ++i) {
                    float val = p0123 * sel3(t4, c1r[4], s1r[4]);
                    float hf, lf;
                    bfsplit(val, hf, lf);
                    if (i & 1) {
                        hw[i >> 1] = __byte_perm(__float_as_uint(prevh), __float_as_uint(hf), 0x7632);
                        lw[i >> 1] = __byte_perm(__float_as_uint(prevl), __float_as_uint(lf), 0x7632);
                    } else { prevh = hf; prevl = lf; }
                    if (++t4 == 3) { t4 = 0;
                        if (++t3 == 3) { t3 = 0;
                            if (++t2 == 3) { t2 = 0;
                                if (++t1 == 3) { t1 = 0; ++t0; g0 = sel3(t0, c1r[0], s1r[0]); }
                                g1 = sel3(t1, c1r[1], s1r[1]);
                            }
                            g2 = sel3(t2, c1r[2], s1r[2]);
                        }
                        g3 = sel3(t3, c1r[3], s1r[3]);
                        p0123 = g0 * g1 * g2 * g3;
                    }
                }
                int vp = wu * 4 + p8;
                *(uint4*)&F1h[(vp * 65 + wb) * 8] = make_uint4(hw[0], hw[1], hw[2], hw[3]);
                *(uint4*)&F1l[(vp * 65 + wb) * 8] = make_uint4(lw[0], lw[1], lw[2], lw[3]);
            }
        }
        __syncthreads();

        // ---- MFMA over this half's 4 K-steps, 1-deep A-frag prefetch ----
        #pragma unroll
        for (int kl = 0; kl < 4; ++kl) {
            int ks = h * 4 + kl;
            uint4 na_h[4], na_l[4];
            if (ks < 7) {                        // compile-time (loops unrolled)
                #pragma unroll
                for (int ut = 0; ut < 4; ++ut) {
                    int idx = ((wave * 4 + ut) * 8 + ks + 1) * 64 + lane;
                    na_h[ut] = Ahi[idx];
                    na_l[ut] = Alo[idx];
                }
            }
            int vp = kl * 4 + (lane >> 4);
            #pragma unroll
            for (int wt = 0; wt < 4; ++wt) {
                int off = (vp * 65 + wt * 16 + (lane & 15)) * 8;
                uint4 b_h = *(const uint4*)&F1h[off];
                uint4 b_l = *(const uint4*)&F1l[off];
                bf16x8 bh = __builtin_bit_cast(bf16x8, b_h);
                bf16x8 bl = __builtin_bit_cast(bf16x8, b_l);
                #pragma unroll
                for (int ut = 0; ut < 4; ++ut) {
                    bf16x8 ah = __builtin_bit_cast(bf16x8, a_h[ut]);
                    bf16x8 al = __builtin_bit_cast(bf16x8, a_l[ut]);
                    acc[ut][wt] = __builtin_amdgcn_mfma_f32_16x16x32_bf16(ah, bh, acc[ut][wt], 0, 0, 0);
                    acc[ut][wt] = __builtin_amdgcn_mfma_f32_16x16x32_bf16(ah, bl, acc[ut][wt], 0, 0, 0);
                    acc[ut][wt] = __builtin_amdgcn_mfma_f32_16x16x32_bf16(al, bh, acc[ut][wt], 0, 0, 0);
                }
            }
            if (ks < 7) {
                #pragma unroll
                for (int ut = 0; ut < 4; ++ut) { a_h[ut] = na_h[ut]; a_l[ut] = na_l[ut]; }
            }
        }
    }

    // ---- epilogue: z[w] = sum_u F0[u,w]*G[u,w] via LDS F0 table (arena reused) ----
    int c = lane & 15;
    float c0b[5], s0b[5];
    #pragma unroll
    for (int k = 0; k < 5; ++k) { c0b[k] = trg[2][wb + k]; s0b[k] = trg[3][wb + k]; }
    float zcol[4] = {0.f, 0.f, 0.f, 0.f};

    __syncthreads();                         // all F1 reads complete before arena overwrite
    #pragma unroll 1
    for (int hp = 0; hp < 2; ++hp) {
        if (hp) __syncthreads();
        {
            int gu = hp * 128 + wu * 32;
            int t0 = gu / 81; int rr = gu - t0 * 81;
            int t1 = rr / 27; rr -= t1 * 27;
            int t2 = rr / 9;  rr -= t2 * 9;
            int t3 = rr / 3;  int t4 = rr - t3 * 3;
            float g0 = sel3(t0, c0b[0], s0b[0]);
            float g1 = sel3(t1, c0b[1], s0b[1]);
            float g2 = sel3(t2, c0b[2], s0b[2]);
            float g3 = sel3(t3, c0b[3], s0b[3]);
            float p0123 = g0 * g1 * g2 * g3;
            #pragma unroll
            for (int s = 0; s < 32; ++s) {
                float val = p0123 * sel3(t4, c0b[4], s0b[4]);   // u>=243 garbage: acc rows are 0
                F0[(wu * 32 + s) * 65 + wb] = val;
                if (++t4 == 3) { t4 = 0;
                    if (++t3 == 3) { t3 = 0;
                        if (++t2 == 3) { t2 = 0;
                            if (++t1 == 3) { t1 = 0; ++t0; g0 = sel3(t0, c0b[0], s0b[0]); }
                            g1 = sel3(t1, c0b[1], s0b[1]);
                        }
                        g2 = sel3(t2, c0b[2], s0b[2]);
                    }
                    g3 = sel3(t3, c0b[3], s0b[3]);
                    p0123 = g0 * g1 * g2 * g3;
                }
            }
        }
        __syncthreads();
        if ((wave >> 1) == hp) {
            int wloc = wave & 1;
            int qb = (lane >> 4) << 2;
            #pragma unroll
            for (int ut = 0; ut < 4; ++ut) {
                #pragma unroll
                for (int r = 0; r < 4; ++r) {
                    int uloc = wloc * 64 + ut * 16 + qb + r;
                    #pragma unroll
                    for (int wt = 0; wt < 4; ++wt)
                        zcol[wt] += F0[uloc * 65 + wt * 16 + c] * acc[ut][wt][r];
                }
            }
        }
    }

    // ---- reduce over u-groups ----
    #pragma unroll
    for (int wt = 0; wt < 4; ++wt) {
        float v = zcol[wt];
        v += __shfl_xor(v, 16, 64);
        v += __shfl_xor(v, 32, 64);
        if ((lane >> 4) == 0) red[wave * 4 + wt][lane] = v;
    }
    __syncthreads();
    if (tid < 64) {
        int wt = tid >> 4, cc = tid & 15;
        float z = red[0 * 4 + wt][cc] + red[1 * 4 + wt][cc]
                + red[2 * 4 + wt][cc] + red[3 * 4 + wt][cc];
        int w = wt * 16 + cc;
        if (w0 + w < NWIN) out[b * NWIN + w0 + w] = z;
    }
}

extern "C" void kernel_launch(void* const* d_in, const int* in_sizes, int n_in,
                              void* d_out, int out_size, void* d_ws, size_t ws_size,
                              hipStream_t stream) {
    const float* x     = (const float*)d_in[0];
    const float* E     = (const float*)d_in[1];
    const float* theta = (const float*)d_in[2];
    float* out = (float*)d_out;
    float* ws = (float*)d_ws;

    uint4* Apk = (uint4*)(ws + APK_OFF);
    float* M   = ws + M_OFF;
    float* Mx  = ws + EXTRA_OFF;

    size_t need4 = (size_t)(EXTRA_OFF + 3 * 1048576) * 4;
    size_t need2 = (size_t)(EXTRA_OFF + 1 * 1048576) * 4;
    int S = (ws_size >= need4) ? 4 : ((ws_size >= need2) ? 2 : 1);

    mgemm_ker<<<dim3(136, 1, S), 256, 0, stream>>>(E, theta, M, Mx);
    if (S > 1) sum_ker<<<1024, 256, 0, stream>>>(M, Mx, S);
    cwht_ker<<<1024, 256, 0, stream>>>(M, (unsigned short*)Apk);
    main_ker<<<dim3(64, 16), 256, 0, stream>>>(x, Apk, out);
}

// Round 15
// 67.581 us; speedup vs baseline: 1.1504x; 1.0450x over previous
//
#include <hip/hip_runtime.h>
#include <math.h>

// Problem constants
#define B_SZ   16
#define L_SZ   4096
#define NWIN   4092      // (4096-5)/1+1
#define U3     243       // 3^5
#define UPAD   256

// ws layout (float offsets): Apk | M | M partials
#define APK_OFF 0                         // 16384 uint4 (hi 8192, lo 8192)
#define M_OFF   65536
#define EXTRA_OFF (M_OFF + 1048576)       // K-split partial buffers

typedef __attribute__((ext_vector_type(8))) __bf16 bf16x8;
typedef __attribute__((ext_vector_type(4))) float f32x4;

__device__ __forceinline__ float sel3(int t, float c, float s) {
    return t == 0 ? 1.0f : (t == 1 ? c : s);
}

// Apk fragment index for element C[u][v]
__device__ __forceinline__ int apk_idx(int u, int v) {
    return (((u >> 4) * 8 + (v >> 5)) * 64 + ((u & 15) | (((v >> 3) & 3) << 4))) * 8 + (v & 7);
}

// truncation split: x = hi(bf16) + lo(bf16), lo absorbs the error
__device__ __forceinline__ void bfsplit(float x, float& hf, float& lf) {
    hf = __uint_as_float(__float_as_uint(x) & 0xFFFF0000u);
    lf = x - hf;
}

// ---------------- M = E^T (G⊗I) E via MFMA 3-term bf16 split ----------------
// symmetric upper-triangle 64x64 blocks (136), z = K-split S; TILE-32 output layout
__global__ __launch_bounds__(256, 4) void mgemm_ker(const float* __restrict__ E,
                                                    const float* __restrict__ theta,
                                                    float* __restrict__ M,
                                                    float* __restrict__ Mp_extra) {
    __shared__ float SA[32][72];
    __shared__ float SB[32][72];
    __shared__ uint4 AfH[4 * 64], AfL[4 * 64];
    __shared__ uint4 BfH[4 * 64], BfL[4 * 64];

    int t = blockIdx.x;
    int bj = 0;
    while (t >= 16 - bj) { t -= 16 - bj; ++bj; }
    int bk = bj + t;
    int ks = blockIdx.z;
    int tid = threadIdx.x;
    int lane = tid & 63;
    int wave = tid >> 6;

    float th = theta[0];
    float st, ct;
    __sincosf(th, &st, &ct);

    f32x4 acc[4];
    #pragma unroll
    for (int kt = 0; kt < 4; ++kt) acc[kt] = (f32x4){0.f, 0.f, 0.f, 0.f};

    int kchunk = 1024 / gridDim.z;
    int k0 = ks * kchunk;
    int lr = tid >> 3;
    int lcq = (tid & 7) * 8;

    for (int d0 = k0; d0 < k0 + kchunk; d0 += 32) {
        bool hi = d0 >= 512;
        int dp = hi ? (d0 - 512) : (d0 + 512);
        float4 a0 = *(const float4*)&E[(d0 + lr) * 1024 + bj * 64 + lcq];
        float4 a1 = *(const float4*)&E[(d0 + lr) * 1024 + bj * 64 + lcq + 4];
        float4 q0 = *(const float4*)&E[(d0 + lr) * 1024 + bk * 64 + lcq];
        float4 q1 = *(const float4*)&E[(d0 + lr) * 1024 + bk * 64 + lcq + 4];
        float4 p0 = *(const float4*)&E[(dp + lr) * 1024 + bk * 64 + lcq];
        float4 p1 = *(const float4*)&E[(dp + lr) * 1024 + bk * 64 + lcq + 4];
        float4 y0, y1;
        if (!hi) {
            y0.x = ct * q0.x - st * p0.x; y0.y = ct * q0.y - st * p0.y;
            y0.z = ct * q0.z - st * p0.z; y0.w = ct * q0.w - st * p0.w;
            y1.x = ct * q1.x - st * p1.x; y1.y = ct * q1.y - st * p1.y;
            y1.z = ct * q1.z - st * p1.z; y1.w = ct * q1.w - st * p1.w;
        } else {
            y0.x = -st * p0.x - ct * q0.x; y0.y = -st * p0.y - ct * q0.y;
            y0.z = -st * p0.z - ct * q0.z; y0.w = -st * p0.w - ct * q0.w;
            y1.x = -st * p1.x - ct * q1.x; y1.y = -st * p1.y - ct * q1.y;
            y1.z = -st * p1.z - ct * q1.z; y1.w = -st * p1.w - ct * q1.w;
        }
        __syncthreads();
        *(float4*)&SA[lr][lcq] = a0;
        *(float4*)&SA[lr][lcq + 4] = a1;
        *(float4*)&SB[lr][lcq] = y0;
        *(float4*)&SB[lr][lcq + 4] = y1;
        __syncthreads();

        {
            unsigned ahw[4], alw[4], bhw[4], blw[4];
            float pah, pal, pbh, pbl;
            #pragma unroll
            for (int i = 0; i < 8; ++i) {
                float av = SA[wave * 8 + i][lane];
                float bv = SB[wave * 8 + i][lane];
                float ah, al, bh, bl;
                bfsplit(av, ah, al);
                bfsplit(bv, bh, bl);
                if (i & 1) {
                    ahw[i >> 1] = __byte_perm(__float_as_uint(pah), __float_as_uint(ah), 0x7632);
                    alw[i >> 1] = __byte_perm(__float_as_uint(pal), __float_as_uint(al), 0x7632);
                    bhw[i >> 1] = __byte_perm(__float_as_uint(pbh), __float_as_uint(bh), 0x7632);
                    blw[i >> 1] = __byte_perm(__float_as_uint(pbl), __float_as_uint(bl), 0x7632);
                } else { pah = ah; pal = al; pbh = bh; pbl = bl; }
            }
            int slot = ((lane >> 4) << 6) + (lane & 15) + (wave << 4);
            AfH[slot] = make_uint4(ahw[0], ahw[1], ahw[2], ahw[3]);
            AfL[slot] = make_uint4(alw[0], alw[1], alw[2], alw[3]);
            BfH[slot] = make_uint4(bhw[0], bhw[1], bhw[2], bhw[3]);
            BfL[slot] = make_uint4(blw[0], blw[1], blw[2], blw[3]);
        }
        __syncthreads();

        uint4 ahu = AfH[wave * 64 + lane];
        uint4 alu = AfL[wave * 64 + lane];
        bf16x8 ah = __builtin_bit_cast(bf16x8, ahu);
        bf16x8 al = __builtin_bit_cast(bf16x8, alu);
        #pragma unroll
        for (int kt = 0; kt < 4; ++kt) {
            uint4 bhu = BfH[kt * 64 + lane];
            uint4 blu = BfL[kt * 64 + lane];
            bf16x8 bh = __builtin_bit_cast(bf16x8, bhu);
            bf16x8 bl = __builtin_bit_cast(bf16x8, blu);
            acc[kt] = __builtin_amdgcn_mfma_f32_16x16x32_bf16(ah, bh, acc[kt], 0, 0, 0);
            acc[kt] = __builtin_amdgcn_mfma_f32_16x16x32_bf16(ah, bl, acc[kt], 0, 0, 0);
            acc[kt] = __builtin_amdgcn_mfma_f32_16x16x32_bf16(al, bh, acc[kt], 0, 0, 0);
        }
    }

    float* dst = (ks == 0) ? M : (Mp_extra + (ks - 1) * 1048576);
    #pragma unroll
    for (int kt = 0; kt < 4; ++kt) {
        #pragma unroll
        for (int i = 0; i < 4; ++i) {
            int r = bj * 64 + wave * 16 + ((lane >> 4) << 2) + i;
            int c = bk * 64 + kt * 16 + (lane & 15);
            dst[((r >> 5) * 32 + (c >> 5)) * 1024 + (r & 31) * 32 + (c & 31)] = acc[kt][i];
        }
    }
}

// ---------------- sum K-split partials into M (coalesced) ----------------
__global__ __launch_bounds__(256) void sum_ker(float* __restrict__ M,
                                               const float* __restrict__ Mp_extra,
                                               int S) {
    int i = blockIdx.x * 256 + threadIdx.x;   // < 262144 float4
    float4 v = ((const float4*)M)[i];
    for (int s = 1; s < S; ++s) {
        float4 p = ((const float4*)(Mp_extra + (s - 1) * 1048576))[i];
        v.x += p.x; v.y += p.y; v.z += p.z; v.w += p.w;
    }
    ((float4*)M)[i] = v;
}

// ---------------- C via WHT (single summed M), scattering bf16 hi/lo into Apk ----------------
__global__ __launch_bounds__(256) void cwht_ker(const float* __restrict__ M,
                                                unsigned short* __restrict__ ApkH) {
    __shared__ float D[1024];
    int mx = blockIdx.x;
    int mxh = mx >> 5, mxl = mx & 31;
    int tid = threadIdx.x;
    float v[4];
    #pragma unroll
    for (int k = 0; k < 4; ++k) {
        int j = tid + k * 256;
        int jh = j >> 5, jl = j & 31;
        int kh = jh ^ mxh, kl = jl ^ mxl;
        int off;
        if ((jh >> 1) <= (kh >> 1)) off = ((jh * 32 + kh) * 32 + jl) * 32 + kl;
        else                        off = ((kh * 32 + jh) * 32 + kl) * 32 + jl;  // symmetric image
        v[k] = M[off];
    }
    #pragma unroll
    for (int s = 0; s < 6; ++s) {
        int bit = (tid >> s) & 1;
        #pragma unroll
        for (int k = 0; k < 4; ++k) {
            float p = __shfl_xor(v[k], 1 << s, 64);
            v[k] = bit ? (p - v[k]) : (v[k] + p);
        }
    }
    #pragma unroll
    for (int k = 0; k < 4; ++k) D[tid + k * 256] = v[k];
    __syncthreads();
    {
        int b6 = (tid >> 6) & 1, b7 = (tid >> 7) & 1;
        #pragma unroll
        for (int k = 0; k < 4; ++k) {
            float p64  = D[(tid ^ 64)  + k * 256];
            float p128 = D[(tid ^ 128) + k * 256];
            float p192 = D[(tid ^ 192) + k * 256];
            float ta = b6 ? (p64 - v[k])   : (v[k] + p64);
            float tb = b6 ? (p192 - p128)  : (p128 + p192);
            v[k] = b7 ? (tb - ta) : (ta + tb);
        }
    }
    {
        float a0 = v[0] + v[1], a1 = v[0] - v[1], a2 = v[2] + v[3], a3 = v[2] - v[3];
        v[0] = a0 + a2; v[1] = a1 + a3; v[2] = a0 - a2; v[3] = a1 - a3;
    }
    #pragma unroll
    for (int k = 0; k < 4; ++k) {
        int mz = tid + k * 256;
        if (mz & mx) continue;
        int u = 0, vv = 0;
        #pragma unroll
        for (int i = 0; i < 5; ++i) {
            int bit = 9 - i;
            int tt = ((mx >> bit) & 1) ? 2 : (((mz >> bit) & 1) ? 1 : 0);
            u = u * 3 + tt;
        }
        #pragma unroll
        for (int i = 5; i < 10; ++i) {
            int bit = 9 - i;
            int tt = ((mx >> bit) & 1) ? 2 : (((mz >> bit) & 1) ? 1 : 0);
            vv = vv * 3 + tt;
        }
        float val = v[k] * (1.0f / 1024.0f);
        unsigned hh = __float_as_uint(val) & 0xFFFF0000u;
        float lf = val - __uint_as_float(hh);
        unsigned ll = __float_as_uint(lf) >> 16;
        int idx = apk_idx(u, vv);
        ApkH[idx] = (unsigned short)(hh >> 16);
        ApkH[idx + 65536] = (unsigned short)ll;
    }
    if (mx == 0) {
        for (int e = tid; e < 13 * 256; e += 256) {
            int u = 243 + (e >> 8), vv = e & 255;
            int idx = apk_idx(u, vv);
            ApkH[idx] = 0; ApkH[idx + 65536] = 0;
        }
        for (int e = tid; e < 243 * 13; e += 256) {
            int u = e / 13, vv = 243 + (e - (e / 13) * 13);
            int idx = apk_idx(u, vv);
            ApkH[idx] = 0; ApkH[idx + 65536] = 0;
        }
    }
}

// ---------------- main: 64 windows/block, MFMA bf16, A hi/lo split x B single-RN ----------------
// F1 SINGLE-PLANE (round-to-nearest bf16): 256 MFMA/wave (was 384), b-reads halved,
// F1 writes halved. R11 structure otherwise; lb(256,3) keeps acc resident, no spill.
__global__ __launch_bounds__(256, 3) void main_ker(const float* __restrict__ x,
                                                   const uint4* __restrict__ Apk,
                                                   float* __restrict__ out) {
    __shared__ float trg[4][68];
    __shared__ __align__(16) unsigned char arena[33280];        // F1 (16640B), then F0[128][65] f32
    unsigned short* F1h = (unsigned short*)arena;               // 16640 B (single plane)
    float* F0 = (float*)arena;                                  // 128*65*4 = 33280 B
    __shared__ float red[16][16];

    int tid = threadIdx.x;
    int w0 = blockIdx.x * 64;
    int b  = blockIdx.y;
    int lane = tid & 63;
    int wave = tid >> 6;
    int wb = tid & 63;
    int wu = __builtin_amdgcn_readfirstlane(wave);   // scalar wave id -> SALU digit chains

    for (int p = tid; p < 68; p += 256) {
        int pos = w0 + p;
        bool ok = pos < L_SZ;
        float x1 = ok ? x[b * 8192 + 4096 + pos] : 0.f;
        float x0 = ok ? x[b * 8192 + pos] : 0.f;
        float c1v, s1v, c0v, s0v;
        __sincosf(x1, &s1v, &c1v);
        __sincosf(x0, &s0v, &c0v);
        if (!ok) { c1v = 0.f; s1v = 0.f; c0v = 0.f; s0v = 0.f; }
        trg[0][p] = c1v; trg[1][p] = s1v; trg[2][p] = c0v; trg[3][p] = s0v;
    }

    f32x4 acc[4][4];
    #pragma unroll
    for (int ut = 0; ut < 4; ++ut)
        #pragma unroll
        for (int wt = 0; wt < 4; ++wt)
            acc[ut][wt] = (f32x4){0.f, 0.f, 0.f, 0.f};

    __syncthreads();

    float c1r[5], s1r[5];
    #pragma unroll
    for (int k = 0; k < 5; ++k) { c1r[k] = trg[0][wb + k]; s1r[k] = trg[1][wb + k]; }

    const uint4* Ahi = Apk;
    const uint4* Alo = Apk + 8192;

    #pragma unroll 1
    for (int h = 0; h < 2; ++h) {
        if (h) __syncthreads();
        // ---- build F1 half h: 32 v per thread, scalar digit walk, RN bf16 single plane ----
        {
            int gv = h * 128 + wu * 32;                 // SGPR
            int t0 = gv / 81; int rr = gv - t0 * 81;
            int t1 = rr / 27; rr -= t1 * 27;
            int t2 = rr / 9;  rr -= t2 * 9;
            int t3 = rr / 3;  int t4 = rr - t3 * 3;
            float g0 = sel3(t0, c1r[0], s1r[0]);
            float g1 = sel3(t1, c1r[1], s1r[1]);
            float g2 = sel3(t2, c1r[2], s1r[2]);
            float g3 = sel3(t3, c1r[3], s1r[3]);
            float p0123 = g0 * g1 * g2 * g3;
            #pragma unroll
            for (int p8 = 0; p8 < 4; ++p8) {
                unsigned hw[4];
                unsigned prevr;
                #pragma unroll
                for (int i = 0; i < 8; ++i) {
                    float val = p0123 * sel3(t4, c1r[4], s1r[4]);
                    unsigned rb = (__float_as_uint(val) + 0x8000u) >> 16;   // RN(half-up) bf16
                    if (i & 1) hw[i >> 1] = prevr | (rb << 16);
                    else       prevr = rb;
                    if (++t4 == 3) { t4 = 0;
                        if (++t3 == 3) { t3 = 0;
                            if (++t2 == 3) { t2 = 0;
                                if (++t1 == 3) { t1 = 0; ++t0; g0 = sel3(t0, c1r[0], s1r[0]); }
                                g1 = sel3(t1, c1r[1], s1r[1]);
                            }
                            g2 = sel3(t2, c1r[2], s1r[2]);
                        }
                        g3 = sel3(t3, c1r[3], s1r[3]);
                        p0123 = g0 * g1 * g2 * g3;
                    }
                }
                int vp = wu * 4 + p8;
                *(uint4*)&F1h[(vp * 65 + wb) * 8] = make_uint4(hw[0], hw[1], hw[2], hw[3]);
            }
        }
        __syncthreads();

        // ---- MFMA over this half's 4 K-steps: 2 terms (ah*b + al*b) ----
        #pragma unroll
        for (int kl = 0; kl < 4; ++kl) {
            int ks = h * 4 + kl;
            uint4 a_h[4], a_l[4];
            #pragma unroll
            for (int ut = 0; ut < 4; ++ut) {
                int idx = ((wave * 4 + ut) * 8 + ks) * 64 + lane;
                a_h[ut] = Ahi[idx];
                a_l[ut] = Alo[idx];
            }
            int vp = kl * 4 + (lane >> 4);
            #pragma unroll
            for (int wt = 0; wt < 4; ++wt) {
                int off = (vp * 65 + wt * 16 + (lane & 15)) * 8;
                uint4 b_u = *(const uint4*)&F1h[off];
                bf16x8 bb = __builtin_bit_cast(bf16x8, b_u);
                #pragma unroll
                for (int ut = 0; ut < 4; ++ut) {
                    bf16x8 ah = __builtin_bit_cast(bf16x8, a_h[ut]);
                    bf16x8 al = __builtin_bit_cast(bf16x8, a_l[ut]);
                    acc[ut][wt] = __builtin_amdgcn_mfma_f32_16x16x32_bf16(ah, bb, acc[ut][wt], 0, 0, 0);
                    acc[ut][wt] = __builtin_amdgcn_mfma_f32_16x16x32_bf16(al, bb, acc[ut][wt], 0, 0, 0);
                }
            }
        }
    }

    // ---- epilogue: z[w] = sum_u F0[u,w]*G[u,w] via LDS F0 table (arena reused) ----
    int c = lane & 15;
    float c0b[5], s0b[5];
    #pragma unroll
    for (int k = 0; k < 5; ++k) { c0b[k] = trg[2][wb + k]; s0b[k] = trg[3][wb + k]; }
    float zcol[4] = {0.f, 0.f, 0.f, 0.f};

    __syncthreads();                         // all F1 reads complete before arena overwrite
    #pragma unroll 1
    for (int hp = 0; hp < 2; ++hp) {
        if (hp) __syncthreads();
        {
            int gu = hp * 128 + wu * 32;     // SGPR
            int t0 = gu / 81; int rr = gu - t0 * 81;
            int t1 = rr / 27; rr -= t1 * 27;
            int t2 = rr / 9;  rr -= t2 * 9;
            int t3 = rr / 3;  int t4 = rr - t3 * 3;
            float g0 = sel3(t0, c0b[0], s0b[0]);
            float g1 = sel3(t1, c0b[1], s0b[1]);
            float g2 = sel3(t2, c0b[2], s0b[2]);
            float g3 = sel3(t3, c0b[3], s0b[3]);
            float p0123 = g0 * g1 * g2 * g3;
            #pragma unroll
            for (int s = 0; s < 32; ++s) {
                float val = p0123 * sel3(t4, c0b[4], s0b[4]);   // u>=243 garbage: acc rows are 0
                F0[(wu * 32 + s) * 65 + wb] = val;
                if (++t4 == 3) { t4 = 0;
                    if (++t3 == 3) { t3 = 0;
                        if (++t2 == 3) { t2 = 0;
                            if (++t1 == 3) { t1 = 0; ++t0; g0 = sel3(t0, c0b[0], s0b[0]); }
                            g1 = sel3(t1, c0b[1], s0b[1]);
                        }
                        g2 = sel3(t2, c0b[2], s0b[2]);
                    }
                    g3 = sel3(t3, c0b[3], s0b[3]);
                    p0123 = g0 * g1 * g2 * g3;
                }
            }
        }
        __syncthreads();
        if ((wave >> 1) == hp) {
            int wloc = wave & 1;
            int qb = (lane >> 4) << 2;
            #pragma unroll
            for (int ut = 0; ut < 4; ++ut) {
                #pragma unroll
                for (int r = 0; r < 4; ++r) {
                    int uloc = wloc * 64 + ut * 16 + qb + r;
                    #pragma unroll
                    for (int wt = 0; wt < 4; ++wt)
                        zcol[wt] += F0[uloc * 65 + wt * 16 + c] * acc[ut][wt][r];
                }
            }
        }
    }

    // ---- reduce over u-groups ----
    #pragma unroll
    for (int wt = 0; wt < 4; ++wt) {
        float v = zcol[wt];
        v += __shfl_xor(v, 16, 64);
        v += __shfl_xor(v, 32, 64);
        if ((lane >> 4) == 0) red[wave * 4 + wt][lane] = v;
    }
    __syncthreads();
    if (tid < 64) {
        int wt = tid >> 4, cc = tid & 15;
        float z = red[0 * 4 + wt][cc] + red[1 * 4 + wt][cc]
                + red[2 * 4 + wt][cc] + red[3 * 4 + wt][cc];
        int w = wt * 16 + cc;
        if (w0 + w < NWIN) out[b * NWIN + w0 + w] = z;
    }
}

extern "C" void kernel_launch(void* const* d_in, const int* in_sizes, int n_in,
                              void* d_out, int out_size, void* d_ws, size_t ws_size,
                              hipStream_t stream) {
    const float* x     = (const float*)d_in[0];
    const float* E     = (const float*)d_in[1];
    const float* theta = (const float*)d_in[2];
    float* out = (float*)d_out;
    float* ws = (float*)d_ws;

    uint4* Apk = (uint4*)(ws + APK_OFF);
    float* M   = ws + M_OFF;
    float* Mx  = ws + EXTRA_OFF;

    size_t need4 = (size_t)(EXTRA_OFF + 3 * 1048576) * 4;
    size_t need2 = (size_t)(EXTRA_OFF + 1 * 1048576) * 4;
    int S = (ws_size >= need4) ? 4 : ((ws_size >= need2) ? 2 : 1);

    mgemm_ker<<<dim3(136, 1, S), 256, 0, stream>>>(E, theta, M, Mx);
    if (S > 1) sum_ker<<<1024, 256, 0, stream>>>(M, Mx, S);
    cwht_ker<<<1024, 256, 0, stream>>>(M, (unsigned short*)Apk);
    main_ker<<<dim3(64, 16), 256, 0, stream>>>(x, Apk, out);
}

// Round 16
// 64.702 us; speedup vs baseline: 1.2015x; 1.0445x over previous
//
#include <hip/hip_runtime.h>
#include <math.h>

// Problem constants
#define B_SZ   16
#define L_SZ   4096
#define NWIN   4092      // (4096-5)/1+1
#define U3     243       // 3^5
#define UPAD   256

// ws layout (float offsets): Apk | M | M partials
#define APK_OFF 0                         // 16384 uint4 (hi 8192, lo 8192)
#define M_OFF   65536
#define EXTRA_OFF (M_OFF + 1048576)       // K-split partial buffers

typedef __attribute__((ext_vector_type(8))) __bf16 bf16x8;
typedef __attribute__((ext_vector_type(4))) float f32x4;

__device__ __forceinline__ float sel3(int t, float c, float s) {
    return t == 0 ? 1.0f : (t == 1 ? c : s);
}

// Apk fragment index for element C[u][v]
__device__ __forceinline__ int apk_idx(int u, int v) {
    return (((u >> 4) * 8 + (v >> 5)) * 64 + ((u & 15) | (((v >> 3) & 3) << 4))) * 8 + (v & 7);
}

// truncation split: x = hi(bf16) + lo(bf16), lo absorbs the error
__device__ __forceinline__ void bfsplit(float x, float& hf, float& lf) {
    hf = __uint_as_float(__float_as_uint(x) & 0xFFFF0000u);
    lf = x - hf;
}

// ---------------- M = E^T (G⊗I) E via MFMA 3-term bf16 split ----------------
__global__ __launch_bounds__(256, 4) void mgemm_ker(const float* __restrict__ E,
                                                    const float* __restrict__ theta,
                                                    float* __restrict__ M,
                                                    float* __restrict__ Mp_extra) {
    __shared__ float SA[32][72];
    __shared__ float SB[32][72];
    __shared__ uint4 AfH[4 * 64], AfL[4 * 64];
    __shared__ uint4 BfH[4 * 64], BfL[4 * 64];

    int t = blockIdx.x;
    int bj = 0;
    while (t >= 16 - bj) { t -= 16 - bj; ++bj; }
    int bk = bj + t;
    int ks = blockIdx.z;
    int tid = threadIdx.x;
    int lane = tid & 63;
    int wave = tid >> 6;

    float th = theta[0];
    float st, ct;
    __sincosf(th, &st, &ct);

    f32x4 acc[4];
    #pragma unroll
    for (int kt = 0; kt < 4; ++kt) acc[kt] = (f32x4){0.f, 0.f, 0.f, 0.f};

    int kchunk = 1024 / gridDim.z;
    int k0 = ks * kchunk;
    int lr = tid >> 3;
    int lcq = (tid & 7) * 8;

    for (int d0 = k0; d0 < k0 + kchunk; d0 += 32) {
        bool hi = d0 >= 512;
        int dp = hi ? (d0 - 512) : (d0 + 512);
        float4 a0 = *(const float4*)&E[(d0 + lr) * 1024 + bj * 64 + lcq];
        float4 a1 = *(const float4*)&E[(d0 + lr) * 1024 + bj * 64 + lcq + 4];
        float4 q0 = *(const float4*)&E[(d0 + lr) * 1024 + bk * 64 + lcq];
        float4 q1 = *(const float4*)&E[(d0 + lr) * 1024 + bk * 64 + lcq + 4];
        float4 p0 = *(const float4*)&E[(dp + lr) * 1024 + bk * 64 + lcq];
        float4 p1 = *(const float4*)&E[(dp + lr) * 1024 + bk * 64 + lcq + 4];
        float4 y0, y1;
        if (!hi) {
            y0.x = ct * q0.x - st * p0.x; y0.y = ct * q0.y - st * p0.y;
            y0.z = ct * q0.z - st * p0.z; y0.w = ct * q0.w - st * p0.w;
            y1.x = ct * q1.x - st * p1.x; y1.y = ct * q1.y - st * p1.y;
            y1.z = ct * q1.z - st * p1.z; y1.w = ct * q1.w - st * p1.w;
        } else {
            y0.x = -st * p0.x - ct * q0.x; y0.y = -st * p0.y - ct * q0.y;
            y0.z = -st * p0.z - ct * q0.z; y0.w = -st * p0.w - ct * q0.w;
            y1.x = -st * p1.x - ct * q1.x; y1.y = -st * p1.y - ct * q1.y;
            y1.z = -st * p1.z - ct * q1.z; y1.w = -st * p1.w - ct * q1.w;
        }
        __syncthreads();
        *(float4*)&SA[lr][lcq] = a0;
        *(float4*)&SA[lr][lcq + 4] = a1;
        *(float4*)&SB[lr][lcq] = y0;
        *(float4*)&SB[lr][lcq + 4] = y1;
        __syncthreads();

        {
            unsigned ahw[4], alw[4], bhw[4], blw[4];
            float pah, pal, pbh, pbl;
            #pragma unroll
            for (int i = 0; i < 8; ++i) {
                float av = SA[wave * 8 + i][lane];
                float bv = SB[wave * 8 + i][lane];
                float ah, al, bh, bl;
                bfsplit(av, ah, al);
                bfsplit(bv, bh, bl);
                if (i & 1) {
                    ahw[i >> 1] = __byte_perm(__float_as_uint(pah), __float_as_uint(ah), 0x7632);
                    alw[i >> 1] = __byte_perm(__float_as_uint(pal), __float_as_uint(al), 0x7632);
                    bhw[i >> 1] = __byte_perm(__float_as_uint(pbh), __float_as_uint(bh), 0x7632);
                    blw[i >> 1] = __byte_perm(__float_as_uint(pbl), __float_as_uint(bl), 0x7632);
                } else { pah = ah; pal = al; pbh = bh; pbl = bl; }
            }
            int slot = ((lane >> 4) << 6) + (lane & 15) + (wave << 4);
            AfH[slot] = make_uint4(ahw[0], ahw[1], ahw[2], ahw[3]);
            AfL[slot] = make_uint4(alw[0], alw[1], alw[2], alw[3]);
            BfH[slot] = make_uint4(bhw[0], bhw[1], bhw[2], bhw[3]);
            BfL[slot] = make_uint4(blw[0], blw[1], blw[2], blw[3]);
        }
        __syncthreads();

        uint4 ahu = AfH[wave * 64 + lane];
        uint4 alu = AfL[wave * 64 + lane];
        bf16x8 ah = __builtin_bit_cast(bf16x8, ahu);
        bf16x8 al = __builtin_bit_cast(bf16x8, alu);
        #pragma unroll
        for (int kt = 0; kt < 4; ++kt) {
            uint4 bhu = BfH[kt * 64 + lane];
            uint4 blu = BfL[kt * 64 + lane];
            bf16x8 bh = __builtin_bit_cast(bf16x8, bhu);
            bf16x8 bl = __builtin_bit_cast(bf16x8, blu);
            acc[kt] = __builtin_amdgcn_mfma_f32_16x16x32_bf16(ah, bh, acc[kt], 0, 0, 0);
            acc[kt] = __builtin_amdgcn_mfma_f32_16x16x32_bf16(ah, bl, acc[kt], 0, 0, 0);
            acc[kt] = __builtin_amdgcn_mfma_f32_16x16x32_bf16(al, bh, acc[kt], 0, 0, 0);
        }
    }

    float* dst = (ks == 0) ? M : (Mp_extra + (ks - 1) * 1048576);
    #pragma unroll
    for (int kt = 0; kt < 4; ++kt) {
        #pragma unroll
        for (int i = 0; i < 4; ++i) {
            int r = bj * 64 + wave * 16 + ((lane >> 4) << 2) + i;
            int c = bk * 64 + kt * 16 + (lane & 15);
            dst[((r >> 5) * 32 + (c >> 5)) * 1024 + (r & 31) * 32 + (c & 31)] = acc[kt][i];
        }
    }
}

// ---------------- sum K-split partials into M (coalesced) ----------------
__global__ __launch_bounds__(256) void sum_ker(float* __restrict__ M,
                                               const float* __restrict__ Mp_extra,
                                               int S) {
    int i = blockIdx.x * 256 + threadIdx.x;
    float4 v = ((const float4*)M)[i];
    for (int s = 1; s < S; ++s) {
        float4 p = ((const float4*)(Mp_extra + (s - 1) * 1048576))[i];
        v.x += p.x; v.y += p.y; v.z += p.z; v.w += p.w;
    }
    ((float4*)M)[i] = v;
}

// ---------------- C via WHT (single summed M), scattering bf16 hi/lo into Apk ----------------
__global__ __launch_bounds__(256) void cwht_ker(const float* __restrict__ M,
                                                unsigned short* __restrict__ ApkH) {
    __shared__ float D[1024];
    int mx = blockIdx.x;
    int mxh = mx >> 5, mxl = mx & 31;
    int tid = threadIdx.x;
    float v[4];
    #pragma unroll
    for (int k = 0; k < 4; ++k) {
        int j = tid + k * 256;
        int jh = j >> 5, jl = j & 31;
        int kh = jh ^ mxh, kl = jl ^ mxl;
        int off;
        if ((jh >> 1) <= (kh >> 1)) off = ((jh * 32 + kh) * 32 + jl) * 32 + kl;
        else                        off = ((kh * 32 + jh) * 32 + kl) * 32 + jl;
        v[k] = M[off];
    }
    #pragma unroll
    for (int s = 0; s < 6; ++s) {
        int bit = (tid >> s) & 1;
        #pragma unroll
        for (int k = 0; k < 4; ++k) {
            float p = __shfl_xor(v[k], 1 << s, 64);
            v[k] = bit ? (p - v[k]) : (v[k] + p);
        }
    }
    #pragma unroll
    for (int k = 0; k < 4; ++k) D[tid + k * 256] = v[k];
    __syncthreads();
    {
        int b6 = (tid >> 6) & 1, b7 = (tid >> 7) & 1;
        #pragma unroll
        for (int k = 0; k < 4; ++k) {
            float p64  = D[(tid ^ 64)  + k * 256];
            float p128 = D[(tid ^ 128) + k * 256];
            float p192 = D[(tid ^ 192) + k * 256];
            float ta = b6 ? (p64 - v[k])   : (v[k] + p64);
            float tb = b6 ? (p192 - p128)  : (p128 + p192);
            v[k] = b7 ? (tb - ta) : (ta + tb);
        }
    }
    {
        float a0 = v[0] + v[1], a1 = v[0] - v[1], a2 = v[2] + v[3], a3 = v[2] - v[3];
        v[0] = a0 + a2; v[1] = a1 + a3; v[2] = a0 - a2; v[3] = a1 - a3;
    }
    #pragma unroll
    for (int k = 0; k < 4; ++k) {
        int mz = tid + k * 256;
        if (mz & mx) continue;
        int u = 0, vv = 0;
        #pragma unroll
        for (int i = 0; i < 5; ++i) {
            int bit = 9 - i;
            int tt = ((mx >> bit) & 1) ? 2 : (((mz >> bit) & 1) ? 1 : 0);
            u = u * 3 + tt;
        }
        #pragma unroll
        for (int i = 5; i < 10; ++i) {
            int bit = 9 - i;
            int tt = ((mx >> bit) & 1) ? 2 : (((mz >> bit) & 1) ? 1 : 0);
            vv = vv * 3 + tt;
        }
        float val = v[k] * (1.0f / 1024.0f);
        unsigned hh = __float_as_uint(val) & 0xFFFF0000u;
        float lf = val - __uint_as_float(hh);
        unsigned ll = __float_as_uint(lf) >> 16;
        int idx = apk_idx(u, vv);
        ApkH[idx] = (unsigned short)(hh >> 16);
        ApkH[idx + 65536] = (unsigned short)ll;
    }
    if (mx == 0) {
        for (int e = tid; e < 13 * 256; e += 256) {
            int u = 243 + (e >> 8), vv = e & 255;
            int idx = apk_idx(u, vv);
            ApkH[idx] = 0; ApkH[idx + 65536] = 0;
        }
        for (int e = tid; e < 243 * 13; e += 256) {
            int u = e / 13, vv = 243 + (e - (e / 13) * 13);
            int idx = apk_idx(u, vv);
            ApkH[idx] = 0; ApkH[idx + 65536] = 0;
        }
    }
}

// ---------------- main: 64 windows/block, A staged via global_load_lds DMA ----------------
// A-frags per ks pulled into wave-private LDS slots by 8 fire-and-forget DMAs + one
// wave-local vmcnt(0) — replaces 64 individually-waited VGPR L2 loads (the R15 stall).
// B single-plane RN bf16; A hi/lo split (2-term MFMA). lb(256,3), ~51.5KB LDS -> 3 blocks/CU.
__global__ __launch_bounds__(256, 3) void main_ker(const float* __restrict__ x,
                                                   const uint4* __restrict__ Apk,
                                                   float* __restrict__ out) {
    __shared__ float trg[4][68];
    // arena: Abuf [0,32768) | F1h [32768,49408); F0[128][65] f32 overlays [0,33280) later
    __shared__ __align__(16) unsigned char arena[49408];
    uint4* Abuf = (uint4*)arena;                                 // 32 slots x 64 lanes x 16B
    unsigned short* F1h = (unsigned short*)(arena + 32768);      // 16640 B (single plane)
    float* F0 = (float*)arena;                                   // 128*65*4 = 33280 B
    __shared__ float red[16][16];

    int tid = threadIdx.x;
    int w0 = blockIdx.x * 64;
    int b  = blockIdx.y;
    int lane = tid & 63;
    int wave = tid >> 6;
    int wb = tid & 63;
    int wu = __builtin_amdgcn_readfirstlane(wave);   // scalar wave id -> SALU digit chains

    for (int p = tid; p < 68; p += 256) {
        int pos = w0 + p;
        bool ok = pos < L_SZ;
        float x1 = ok ? x[b * 8192 + 4096 + pos] : 0.f;
        float x0 = ok ? x[b * 8192 + pos] : 0.f;
        float c1v, s1v, c0v, s0v;
        __sincosf(x1, &s1v, &c1v);
        __sincosf(x0, &s0v, &c0v);
        if (!ok) { c1v = 0.f; s1v = 0.f; c0v = 0.f; s0v = 0.f; }
        trg[0][p] = c1v; trg[1][p] = s1v; trg[2][p] = c0v; trg[3][p] = s0v;
    }

    f32x4 acc[4][4];
    #pragma unroll
    for (int ut = 0; ut < 4; ++ut)
        #pragma unroll
        for (int wt = 0; wt < 4; ++wt)
            acc[ut][wt] = (f32x4){0.f, 0.f, 0.f, 0.f};

    __syncthreads();

    float c1r[5], s1r[5];
    #pragma unroll
    for (int k = 0; k < 5; ++k) { c1r[k] = trg[0][wb + k]; s1r[k] = trg[1][wb + k]; }

    #pragma unroll 1
    for (int h = 0; h < 2; ++h) {
        if (h) __syncthreads();
        // ---- build F1 half h: 32 v per thread, scalar digit walk, RN bf16 single plane ----
        {
            int gv = h * 128 + wu * 32;                 // SGPR
            int t0 = gv / 81; int rr = gv - t0 * 81;
            int t1 = rr / 27; rr -= t1 * 27;
            int t2 = rr / 9;  rr -= t2 * 9;
            int t3 = rr / 3;  int t4 = rr - t3 * 3;
            float g0 = sel3(t0, c1r[0], s1r[0]);
            float g1 = sel3(t1, c1r[1], s1r[1]);
            float g2 = sel3(t2, c1r[2], s1r[2]);
            float g3 = sel3(t3, c1r[3], s1r[3]);
            float p0123 = g0 * g1 * g2 * g3;
            #pragma unroll
            for (int p8 = 0; p8 < 4; ++p8) {
                unsigned hw[4];
                unsigned prevr;
                #pragma unroll
                for (int i = 0; i < 8; ++i) {
                    float val = p0123 * sel3(t4, c1r[4], s1r[4]);
                    unsigned rb = (__float_as_uint(val) + 0x8000u) >> 16;   // RN bf16
                    if (i & 1) hw[i >> 1] = prevr | (rb << 16);
                    else       prevr = rb;
                    if (++t4 == 3) { t4 = 0;
                        if (++t3 == 3) { t3 = 0;
                            if (++t2 == 3) { t2 = 0;
                                if (++t1 == 3) { t1 = 0; ++t0; g0 = sel3(t0, c1r[0], s1r[0]); }
                                g1 = sel3(t1, c1r[1], s1r[1]);
                            }
                            g2 = sel3(t2, c1r[2], s1r[2]);
                        }
                        g3 = sel3(t3, c1r[3], s1r[3]);
                        p0123 = g0 * g1 * g2 * g3;
                    }
                }
                int vp = wu * 4 + p8;
                *(uint4*)&F1h[(vp * 65 + wb) * 8] = make_uint4(hw[0], hw[1], hw[2], hw[3]);
            }
        }
        __syncthreads();

        // ---- MFMA over this half's 4 K-steps; A via wave-private LDS DMA staging ----
        #pragma unroll
        for (int kl = 0; kl < 4; ++kl) {
            int ks = h * 4 + kl;
            // issue 8 fire-and-forget DMAs: Apk -> Abuf[wave][ut][pl] (wave-private slots)
            #pragma unroll
            for (int ut = 0; ut < 4; ++ut) {
                #pragma unroll
                for (int pl = 0; pl < 2; ++pl) {
                    int gidx = pl * 8192 + ((wave * 4 + ut) * 8 + ks) * 64 + lane;
                    int slot = (wave * 4 + ut) * 2 + pl;
                    __builtin_amdgcn_global_load_lds(
                        (const __attribute__((address_space(1))) unsigned int*)(Apk + gidx),
                        (__attribute__((address_space(3))) unsigned int*)(Abuf + slot * 64 + lane),
                        16, 0, 0);
                }
            }
            asm volatile("s_waitcnt vmcnt(0)" ::: "memory");   // wave-local: own slots only
            __builtin_amdgcn_sched_barrier(0);
            int vp = kl * 4 + (lane >> 4);
            #pragma unroll
            for (int wt = 0; wt < 4; ++wt) {
                int off = (vp * 65 + wt * 16 + (lane & 15)) * 8;
                uint4 b_u = *(const uint4*)&F1h[off];
                bf16x8 bb = __builtin_bit_cast(bf16x8, b_u);
                #pragma unroll
                for (int ut = 0; ut < 4; ++ut) {
                    uint4 ahu = Abuf[((wave * 4 + ut) * 2 + 0) * 64 + lane];
                    uint4 alu = Abuf[((wave * 4 + ut) * 2 + 1) * 64 + lane];
                    bf16x8 ah = __builtin_bit_cast(bf16x8, ahu);
                    bf16x8 al = __builtin_bit_cast(bf16x8, alu);
                    acc[ut][wt] = __builtin_amdgcn_mfma_f32_16x16x32_bf16(ah, bb, acc[ut][wt], 0, 0, 0);
                    acc[ut][wt] = __builtin_amdgcn_mfma_f32_16x16x32_bf16(al, bb, acc[ut][wt], 0, 0, 0);
                }
            }
        }
    }

    // ---- epilogue: z[w] = sum_u F0[u,w]*G[u,w] via LDS F0 table (arena reused) ----
    int c = lane & 15;
    float c0b[5], s0b[5];
    #pragma unroll
    for (int k = 0; k < 5; ++k) { c0b[k] = trg[2][wb + k]; s0b[k] = trg[3][wb + k]; }
    float zcol[4] = {0.f, 0.f, 0.f, 0.f};

    __syncthreads();                         // all F1/Abuf reads complete before overwrite
    #pragma unroll 1
    for (int hp = 0; hp < 2; ++hp) {
        if (hp) __syncthreads();
        {
            int gu = hp * 128 + wu * 32;     // SGPR
            int t0 = gu / 81; int rr = gu - t0 * 81;
            int t1 = rr / 27; rr -= t1 * 27;
            int t2 = rr / 9;  rr -= t2 * 9;
            int t3 = rr / 3;  int t4 = rr - t3 * 3;
            float g0 = sel3(t0, c0b[0], s0b[0]);
            float g1 = sel3(t1, c0b[1], s0b[1]);
            float g2 = sel3(t2, c0b[2], s0b[2]);
            float g3 = sel3(t3, c0b[3], s0b[3]);
            float p0123 = g0 * g1 * g2 * g3;
            #pragma unroll
            for (int s = 0; s < 32; ++s) {
                float val = p0123 * sel3(t4, c0b[4], s0b[4]);   // u>=243 garbage: acc rows are 0
                F0[(wu * 32 + s) * 65 + wb] = val;
                if (++t4 == 3) { t4 = 0;
                    if (++t3 == 3) { t3 = 0;
                        if (++t2 == 3) { t2 = 0;
                            if (++t1 == 3) { t1 = 0; ++t0; g0 = sel3(t0, c0b[0], s0b[0]); }
                            g1 = sel3(t1, c0b[1], s0b[1]);
                        }
                        g2 = sel3(t2, c0b[2], s0b[2]);
                    }
                    g3 = sel3(t3, c0b[3], s0b[3]);
                    p0123 = g0 * g1 * g2 * g3;
                }
            }
        }
        __syncthreads();
        if ((wave >> 1) == hp) {
            int wloc = wave & 1;
            int qb = (lane >> 4) << 2;
            #pragma unroll
            for (int ut = 0; ut < 4; ++ut) {
                #pragma unroll
                for (int r = 0; r < 4; ++r) {
                    int uloc = wloc * 64 + ut * 16 + qb + r;
                    #pragma unroll
                    for (int wt = 0; wt < 4; ++wt)
                        zcol[wt] += F0[uloc * 65 + wt * 16 + c] * acc[ut][wt][r];
                }
            }
        }
    }

    // ---- reduce over u-groups ----
    #pragma unroll
    for (int wt = 0; wt < 4; ++wt) {
        float v = zcol[wt];
        v += __shfl_xor(v, 16, 64);
        v += __shfl_xor(v, 32, 64);
        if ((lane >> 4) == 0) red[wave * 4 + wt][lane] = v;
    }
    __syncthreads();
    if (tid < 64) {
        int wt = tid >> 4, cc = tid & 15;
        float z = red[0 * 4 + wt][cc] + red[1 * 4 + wt][cc]
                + red[2 * 4 + wt][cc] + red[3 * 4 + wt][cc];
        int w = wt * 16 + cc;
        if (w0 + w < NWIN) out[b * NWIN + w0 + w] = z;
    }
}

extern "C" void kernel_launch(void* const* d_in, const int* in_sizes, int n_in,
                              void* d_out, int out_size, void* d_ws, size_t ws_size,
                              hipStream_t stream) {
    const float* x     = (const float*)d_in[0];
    const float* E     = (const float*)d_in[1];
    const float* theta = (const float*)d_in[2];
    float* out = (float*)d_out;
    float* ws = (float*)d_ws;

    uint4* Apk = (uint4*)(ws + APK_OFF);
    float* M   = ws + M_OFF;
    float* Mx  = ws + EXTRA_OFF;

    size_t need4 = (size_t)(EXTRA_OFF + 3 * 1048576) * 4;
    size_t need2 = (size_t)(EXTRA_OFF + 1 * 1048576) * 4;
    int S = (ws_size >= need4) ? 4 : ((ws_size >= need2) ? 2 : 1);

    mgemm_ker<<<dim3(136, 1, S), 256, 0, stream>>>(E, theta, M, Mx);
    if (S > 1) sum_ker<<<1024, 256, 0, stream>>>(M, Mx, S);
    cwht_ker<<<1024, 256, 0, stream>>>(M, (unsigned short*)Apk);
    main_ker<<<dim3(64, 16), 256, 0, stream>>>(x, Apk, out);
}